// Round 11
// baseline (149.154 us; speedup 1.0000x reference)
//
#include <hip/hip_runtime.h>

#define THREADS 128
#define IPB 2   // images per block; grid = batch/2 = 4096

typedef _Float16 f16;
typedef _Float16 f16x2 __attribute__((ext_vector_type(2)));
typedef _Float16 f16x8 __attribute__((ext_vector_type(8)));
typedef float f32x4 __attribute__((ext_vector_type(4)));
typedef float f32x16 __attribute__((ext_vector_type(16)));
typedef unsigned int uint;

__device__ __forceinline__ f16x2 pkrtz(float a, float b) {
    return __builtin_bit_cast(f16x2, __builtin_amdgcn_cvt_pkrtz(a, b));
}
template<int CTRL>
__device__ __forceinline__ float dppmax(float v) {   // fmax with DPP-shuffled lane
    const int i = __builtin_bit_cast(int, v);
    const int s = __builtin_amdgcn_update_dpp(i, i, CTRL, 0xF, 0xF, true);
    return fmaxf(v, __builtin_bit_cast(float, s));
}

// p1 layout: [img][iy 12][ix 12][ic 16] f16. Row stride 400B; final row unpadded
// so img stride = 11*400+384 = 4784B. ic 10..15 zeros (K-pad).
#define P1_ROW 400
#define P1_IMG 4784

// d_ws layout: [0)      w1pk   250 x uint (dup f16 pairs)
//              [1024)   w2af   1000 x f16x8  (conv2 A-frags [s][oc*2+hK])
//              [17408)  wl1pk  2560 x f16x8  (fc1 A-frags [tile][s][lane])
__global__ void pack_weights(const float* __restrict__ w1,
                             const float* __restrict__ w2,
                             const float* __restrict__ wl1,
                             unsigned char* __restrict__ ws) {
    uint* w1pk  = (uint*)ws;
    f16x8* w2af = (f16x8*)(ws + 1024);
    f16x8* wl1pk = (f16x8*)(ws + 17408);
    const int gid = blockIdx.x * blockDim.x + threadIdx.x;
    const int gsz = gridDim.x * blockDim.x;
    for (int i = gid; i < 250; i += gsz) {
        const unsigned short u =
            __builtin_bit_cast(unsigned short, (f16)w1[i]);
        w1pk[i] = (uint)u | ((uint)u << 16);
    }
    for (int e = gid; e < 1000; e += gsz) {          // conv2 A-frags
        const int s = e / 40, r = e - s * 40;
        const int oc = r >> 1, h = r & 1;
        f16x8 a;
        #pragma unroll
        for (int j = 0; j < 8; ++j) {
            const int ic = h * 8 + j;
            a[j] = (f16)(ic < 10 ? w2[(oc * 10 + ic) * 25 + s] : 0.f);
        }
        w2af[e] = a;
    }
    for (int e = gid; e < 2560; e += gsz) {          // fc1 A-frags
        const int tile = e / 640, rem = e % 640;
        const int s = rem / 64, lane = rem % 64;
        const int m = lane & 15, quad = lane >> 4;
        const int hh = tile * 16 + m;
        f16x8 a;
        #pragma unroll
        for (int j = 0; j < 8; ++j)
            a[j] = (f16)(hh < 50 ? wl1[hh * 320 + s * 32 + quad * 8 + j] : 0.f);
        wl1pk[e] = a;
    }
}

// LDS: p1c 2*4784=9568 + p2h 2*320*2=1280 + h1 2*52*4=416 = 11264 B
//    = 22 x 512B granules -> 14 blocks/CU (28 waves, 87% occupancy ceiling).
__global__ __launch_bounds__(THREADS, 7)
void lenet_one(const float* __restrict__ x,
               const unsigned char* __restrict__ ws, const float* __restrict__ b1,
               const float* __restrict__ b2,
               const float* __restrict__ bl1,
               const float* __restrict__ wl2, const float* __restrict__ bl2,
               float* __restrict__ out, int batch)
{
    __shared__ __align__(16) unsigned char p1c[IPB * P1_IMG];
    __shared__ __align__(16) f16 p2h[IPB * 320];  // [img][k 320]
    __shared__ float h1[IPB * 52];                // [img][50 pad 52]

    const uint*  w1pk  = (const uint*)ws;
    const f16x8* w2af  = (const f16x8*)(ws + 1024);
    const f16x8* wl1pk = (const f16x8*)(ws + 17408);

    const int tid = threadIdx.x;
    const int lane = tid & 63;
    const int wv_ = tid >> 6;                 // wave id 0..1
    const int cM = lane & 31, hK = lane >> 5; // conv2 MFMA: row m=cM, K-half hK

    // ---------- conv1 (1->10ch) packed f16 + bias + relu + pool ---------------
    // wave <-> image: all of a wave's x loads come from one 3KB image (L1-local)
    {
        const int img = wv_;
        const int imgg = min(blockIdx.x * IPB + img, batch - 1);
        const float* xim = x + (size_t)imgg * 784;
        for (int pq = lane; pq < 144; pq += 64) {
            const int py = pq / 12, px = pq % 12;
            const float* xb = xim + (2 * py) * 28 + 2 * px;
            float win[36];
            #pragma unroll
            for (int r = 0; r < 6; ++r)
                #pragma unroll
                for (int cc = 0; cc < 6; ++cc)
                    win[r * 6 + cc] = xb[r * 28 + cc];
            f16x2 pr[30];                         // shifted pairs, reused x10 ch
            #pragma unroll
            for (int r = 0; r < 6; ++r)
                #pragma unroll
                for (int cc = 0; cc < 5; ++cc)
                    pr[r * 5 + cc] = pkrtz(win[r * 6 + cc], win[r * 6 + cc + 1]);
            f16 ch[10];
            #pragma unroll
            for (int c = 0; c < 10; ++c) {
                f16x2 accT = {(f16)0.f, (f16)0.f};
                f16x2 accB = {(f16)0.f, (f16)0.f};
                #pragma unroll
                for (int ky = 0; ky < 5; ++ky)
                    #pragma unroll
                    for (int kx = 0; kx < 5; ++kx) {
                        const uint wp = w1pk[c * 25 + ky * 5 + kx]; // sgpr
                        const f16x2 wv = __builtin_bit_cast(f16x2, wp);
                        accT += pr[ky * 5 + kx] * wv;        // v_pk_fma_f16
                        accB += pr[(ky + 1) * 5 + kx] * wv;
                    }
                const float q0 = fmaxf((float)accT[0], (float)accB[0]);
                const float q1 = fmaxf((float)accT[1], (float)accB[1]);
                ch[c] = (f16)fmaxf(fmaxf(q0, q1) + b1[c], 0.f);
            }
            f16x8 v0, v1;
            #pragma unroll
            for (int j = 0; j < 8; ++j) v0[j] = ch[j];
            v1[0] = ch[8]; v1[1] = ch[9];
            #pragma unroll
            for (int j = 2; j < 8; ++j) v1[j] = (f16)0.f;   // K-pad zeros
            unsigned char* dst = p1c + img * P1_IMG + py * P1_ROW + px * 32;
            *(f16x8*)(dst)      = v0;
            *(f16x8*)(dst + 16) = v1;
        }
    }
    __syncthreads();

    // ---------- conv2 via mfma_f32_32x32x16_f16; A-frags from global ----------
    {
        const int cy = cM >> 3, cx = cM & 7;
        const int afoff = (cM < 20 ? cM : 19) * 2 + hK;
        int bb[2];
        #pragma unroll
        for (int q = 0; q < 2; ++q) {
            const int t = wv_ * 2 + q, im = t >> 1, h2 = t & 1;
            bb[q] = im * P1_IMG + (4 * h2 + cy) * P1_ROW + cx * 32 + hK * 16;
        }
        f32x16 acc[2];
        #pragma unroll
        for (int q = 0; q < 2; ++q)
            #pragma unroll
            for (int r = 0; r < 16; ++r) acc[q][r] = 0.f;
        #pragma unroll 1
        for (int ky = 0; ky < 5; ++ky) {
            #pragma unroll
            for (int kx = 0; kx < 5; ++kx) {
                const f16x8 a = w2af[(ky * 5 + kx) * 40 + afoff];
                #pragma unroll
                for (int q = 0; q < 2; ++q) {
                    const f16x8 b =
                        *(const f16x8*)(p1c + bb[q] + ky * P1_ROW + kx * 32);
                    acc[q] = __builtin_amdgcn_mfma_f32_32x32x16_f16(a, b, acc[q],
                                                                    0, 0, 0);
                }
            }
        }
        // epilogue: pool via DPP (xor1 = quad_perm(1,0,3,2)=0xB1; xor8 = row_ror:8)
        #pragma unroll
        for (int q = 0; q < 2; ++q) {
            const int t = wv_ * 2 + q, im = t >> 1, h2 = t & 1;
            #pragma unroll
            for (int r = 0; r < 16; ++r) {
                const int m = (r & 3) + 8 * (r >> 2) + 4 * hK;
                float v = acc[q][r];
                v = dppmax<0xB1>(v);
                v = dppmax<0x128>(v);
                if (m < 20 && (lane & 9) == 0) {
                    const int py = 2 * h2 + (cM >> 4), px = cx >> 1;
                    p2h[im * 320 + m * 16 + py * 4 + px] =
                        (f16)fmaxf(v + b2[m], 0.f);
                }
            }
        }
    }
    __syncthreads();

    // ---------- fc1 via mfma_f32_16x16x32_f16: 2 h-tiles/wave, B shared -------
    {
        const int n = lane & 15, quad = lane >> 4;
        f32x4 facc[2] = {{0.f, 0.f, 0.f, 0.f}, {0.f, 0.f, 0.f, 0.f}};
        #pragma unroll 1
        for (int s = 0; s < 10; ++s) {
            f16x8 b = {};
            if (n < IPB)
                b = *(const f16x8*)(p2h + n * 320 + s * 32 + quad * 8);
            #pragma unroll
            for (int ht = 0; ht < 2; ++ht) {
                const f16x8 a =
                    wl1pk[((wv_ * 2 + ht) * 10 + s) * 64 + lane];  // b128 coalesced
                facc[ht] = __builtin_amdgcn_mfma_f32_16x16x32_f16(a, b, facc[ht],
                                                                  0, 0, 0);
            }
        }
        if (n < IPB) {
            #pragma unroll
            for (int ht = 0; ht < 2; ++ht)
                #pragma unroll
                for (int r = 0; r < 4; ++r) {
                    const int h = (wv_ * 2 + ht) * 16 + quad * 4 + r;
                    if (h < 50)
                        h1[n * 52 + h] = fmaxf(facc[ht][r] + bl1[h], 0.f);
                }
        }
    }
    __syncthreads();

    // ---------- fc2: 50->10 ---------------------------------------------------
    if (tid < IPB * 10) {
        const int im = tid / 10, o = tid % 10;
        const int imgo = min(blockIdx.x * IPB + im, batch - 1);
        float a = bl2[o];
        #pragma unroll
        for (int h = 0; h < 50; ++h)
            a += h1[im * 52 + h] * wl2[o * 50 + h];
        out[(size_t)imgo * 10 + o] = a;          // coalesced
    }
}

extern "C" void kernel_launch(void* const* d_in, const int* in_sizes, int n_in,
                              void* d_out, int out_size, void* d_ws, size_t ws_size,
                              hipStream_t stream) {
    const float* x   = (const float*)d_in[0];
    const float* w1  = (const float*)d_in[1];
    const float* b1  = (const float*)d_in[2];
    const float* w2  = (const float*)d_in[3];
    const float* b2  = (const float*)d_in[4];
    const float* wl1 = (const float*)d_in[5];
    const float* bl1 = (const float*)d_in[6];
    const float* wl2 = (const float*)d_in[7];
    const float* bl2 = (const float*)d_in[8];
    float* out = (float*)d_out;
    unsigned char* ws = (unsigned char*)d_ws;   // 58 KB of packed weights

    const int batch = in_sizes[0] / 784;  // 8192
    pack_weights<<<16, 256, 0, stream>>>(w1, w2, wl1, ws);
    const int grid = (batch + IPB - 1) / IPB;
    lenet_one<<<grid, THREADS, 0, stream>>>(x, ws, b1, b2, bl1, wl2, bl2,
                                            out, batch);
}

// Round 12
// 140.821 us; speedup vs baseline: 1.0592x; 1.0592x over previous
//
#include <hip/hip_runtime.h>

#define THREADS 256
#define IPB 4   // images per block; grid = batch/4 = 2048

typedef _Float16 f16;
typedef _Float16 f16x2 __attribute__((ext_vector_type(2)));
typedef _Float16 f16x8 __attribute__((ext_vector_type(8)));
typedef float f32x4 __attribute__((ext_vector_type(4)));
typedef float f32x16 __attribute__((ext_vector_type(16)));
typedef unsigned int uint;

__device__ __forceinline__ f16x2 pkrtz(float a, float b) {
    return __builtin_bit_cast(f16x2, __builtin_amdgcn_cvt_pkrtz(a, b));
}
template<int CTRL>
__device__ __forceinline__ float dppmax(float v) {   // fmax with DPP-shuffled lane
    const int i = __builtin_bit_cast(int, v);
    const int s = __builtin_amdgcn_update_dpp(i, i, CTRL, 0xF, 0xF, true);
    return fmaxf(v, __builtin_bit_cast(float, s));
}

// p1 layout: [img][iy 12][ix 12][ic 16] f16. Row stride 400B; final row unpadded
// so img stride = 11*400+384 = 4784B. ic 10..15 zeros (K-pad).
#define P1_ROW 400
#define P1_IMG 4784

// d_ws layout: [0)      w1pk   250 x uint (dup f16 pairs)
//              [1024)   w2af   1000 x f16x8  (conv2 A-frags [s][oc*2+hK])
//              [17408)  wl1pk  2560 x f16x8  (fc1 A-frags [tile][s][lane])
__global__ void pack_weights(const float* __restrict__ w1,
                             const float* __restrict__ w2,
                             const float* __restrict__ wl1,
                             unsigned char* __restrict__ ws) {
    uint* w1pk  = (uint*)ws;
    f16x8* w2af = (f16x8*)(ws + 1024);
    f16x8* wl1pk = (f16x8*)(ws + 17408);
    const int gid = blockIdx.x * blockDim.x + threadIdx.x;
    const int gsz = gridDim.x * blockDim.x;
    for (int i = gid; i < 250; i += gsz) {
        const unsigned short u =
            __builtin_bit_cast(unsigned short, (f16)w1[i]);
        w1pk[i] = (uint)u | ((uint)u << 16);
    }
    for (int e = gid; e < 1000; e += gsz) {          // conv2 A-frags
        const int s = e / 40, r = e - s * 40;
        const int oc = r >> 1, h = r & 1;
        f16x8 a;
        #pragma unroll
        for (int j = 0; j < 8; ++j) {
            const int ic = h * 8 + j;
            a[j] = (f16)(ic < 10 ? w2[(oc * 10 + ic) * 25 + s] : 0.f);
        }
        w2af[e] = a;
    }
    for (int e = gid; e < 2560; e += gsz) {          // fc1 A-frags
        const int tile = e / 640, rem = e % 640;
        const int s = rem / 64, lane = rem % 64;
        const int m = lane & 15, quad = lane >> 4;
        const int hh = tile * 16 + m;
        f16x8 a;
        #pragma unroll
        for (int j = 0; j < 8; ++j)
            a[j] = (f16)(hh < 50 ? wl1[hh * 320 + s * 32 + quad * 8 + j] : 0.f);
        wl1pk[e] = a;
    }
}

// LDS: p1c 4*4784=19136 + p2h 4*320*2=2560 + h1 4*52*4=832 = 22528 B
//    = 44 x 512B granules -> 7 blocks/CU (28 waves). grid 2048 = 8/CU -> one
//    resident generation + 1 tail block per CU.
__global__ __launch_bounds__(THREADS, 7)
void lenet_one(const float* __restrict__ x,
               const unsigned char* __restrict__ ws, const float* __restrict__ b1,
               const float* __restrict__ b2,
               const float* __restrict__ bl1,
               const float* __restrict__ wl2, const float* __restrict__ bl2,
               float* __restrict__ out, int batch)
{
    __shared__ __align__(16) unsigned char p1c[IPB * P1_IMG];
    __shared__ __align__(16) f16 p2h[IPB * 320];  // [img][k 320]
    __shared__ float h1[IPB * 52];                // [img][50 pad 52]

    const uint*  w1pk  = (const uint*)ws;
    const f16x8* w2af  = (const f16x8*)(ws + 1024);
    const f16x8* wl1pk = (const f16x8*)(ws + 17408);

    const int tid = threadIdx.x;
    const int lane = tid & 63;
    const int wv_ = tid >> 6;                 // wave id 0..3
    const int cM = lane & 31, hK = lane >> 5; // conv2 MFMA: row m=cM, K-half hK

    // ---------- conv1 (1->10ch) packed f16 + bias + relu + pool ---------------
    // wave <-> image: wave-uniform image base (scalar), all x loads L1-local.
    {
        const int img = wv_;
        const int imgg = min(blockIdx.x * IPB + img, batch - 1);
        const float* xim = x + (size_t)imgg * 784;
        for (int pq = lane; pq < 144; pq += 64) {
            const int py = pq / 12, px = pq % 12;
            const float* xb = xim + (2 * py) * 28 + 2 * px;
            float win[36];
            #pragma unroll
            for (int r = 0; r < 6; ++r)
                #pragma unroll
                for (int cc = 0; cc < 6; ++cc)
                    win[r * 6 + cc] = xb[r * 28 + cc];
            f16x2 pr[30];                         // shifted pairs, reused x10 ch
            #pragma unroll
            for (int r = 0; r < 6; ++r)
                #pragma unroll
                for (int cc = 0; cc < 5; ++cc)
                    pr[r * 5 + cc] = pkrtz(win[r * 6 + cc], win[r * 6 + cc + 1]);
            f16 ch[10];
            #pragma unroll
            for (int c = 0; c < 10; ++c) {
                f16x2 accT = {(f16)0.f, (f16)0.f};
                f16x2 accB = {(f16)0.f, (f16)0.f};
                #pragma unroll
                for (int ky = 0; ky < 5; ++ky)
                    #pragma unroll
                    for (int kx = 0; kx < 5; ++kx) {
                        const uint wp = w1pk[c * 25 + ky * 5 + kx]; // sgpr
                        const f16x2 wv = __builtin_bit_cast(f16x2, wp);
                        accT += pr[ky * 5 + kx] * wv;        // v_pk_fma_f16
                        accB += pr[(ky + 1) * 5 + kx] * wv;
                    }
                const float q0 = fmaxf((float)accT[0], (float)accB[0]);
                const float q1 = fmaxf((float)accT[1], (float)accB[1]);
                ch[c] = (f16)fmaxf(fmaxf(q0, q1) + b1[c], 0.f);
            }
            f16x8 v0, v1;
            #pragma unroll
            for (int j = 0; j < 8; ++j) v0[j] = ch[j];
            v1[0] = ch[8]; v1[1] = ch[9];
            #pragma unroll
            for (int j = 2; j < 8; ++j) v1[j] = (f16)0.f;   // K-pad zeros
            unsigned char* dst = p1c + img * P1_IMG + py * P1_ROW + px * 32;
            *(f16x8*)(dst)      = v0;
            *(f16x8*)(dst + 16) = v1;
        }
    }
    __syncthreads();

    // ---------- conv2 via mfma_f32_32x32x16_f16; A-frags from global ----------
    {
        const int cy = cM >> 3, cx = cM & 7;
        const int afoff = (cM < 20 ? cM : 19) * 2 + hK;
        int bb[2];
        #pragma unroll
        for (int q = 0; q < 2; ++q) {
            const int t = wv_ * 2 + q, im = t >> 1, h2 = t & 1;
            bb[q] = im * P1_IMG + (4 * h2 + cy) * P1_ROW + cx * 32 + hK * 16;
        }
        f32x16 acc[2];
        #pragma unroll
        for (int q = 0; q < 2; ++q)
            #pragma unroll
            for (int r = 0; r < 16; ++r) acc[q][r] = 0.f;
        #pragma unroll 1
        for (int ky = 0; ky < 5; ++ky) {
            #pragma unroll
            for (int kx = 0; kx < 5; ++kx) {
                const f16x8 a = w2af[(ky * 5 + kx) * 40 + afoff];
                #pragma unroll
                for (int q = 0; q < 2; ++q) {
                    const f16x8 b =
                        *(const f16x8*)(p1c + bb[q] + ky * P1_ROW + kx * 32);
                    acc[q] = __builtin_amdgcn_mfma_f32_32x32x16_f16(a, b, acc[q],
                                                                    0, 0, 0);
                }
            }
        }
        // epilogue: pool via DPP (xor1 = quad_perm(1,0,3,2)=0xB1; xor8 = row_ror:8)
        #pragma unroll
        for (int q = 0; q < 2; ++q) {
            const int t = wv_ * 2 + q, im = t >> 1, h2 = t & 1;
            #pragma unroll
            for (int r = 0; r < 16; ++r) {
                const int m = (r & 3) + 8 * (r >> 2) + 4 * hK;
                float v = acc[q][r];
                v = dppmax<0xB1>(v);
                v = dppmax<0x128>(v);
                if (m < 20 && (lane & 9) == 0) {
                    const int py = 2 * h2 + (cM >> 4), px = cx >> 1;
                    p2h[im * 320 + m * 16 + py * 4 + px] =
                        (f16)fmaxf(v + b2[m], 0.f);
                }
            }
        }
    }
    __syncthreads();

    // ---------- fc1 via mfma_f32_16x16x32_f16: 1 h-tile/wave, N=img -----------
    {
        const int n = lane & 15, quad = lane >> 4;
        f32x4 facc = {0.f, 0.f, 0.f, 0.f};
        #pragma unroll 1
        for (int s = 0; s < 10; ++s) {
            const f16x8 a = wl1pk[(wv_ * 10 + s) * 64 + lane];  // b128 coalesced
            f16x8 b = {};
            if (n < IPB)
                b = *(const f16x8*)(p2h + n * 320 + s * 32 + quad * 8);
            facc = __builtin_amdgcn_mfma_f32_16x16x32_f16(a, b, facc, 0, 0, 0);
        }
        if (n < IPB) {
            #pragma unroll
            for (int r = 0; r < 4; ++r) {
                const int h = wv_ * 16 + quad * 4 + r;
                if (h < 50)
                    h1[n * 52 + h] = fmaxf(facc[r] + bl1[h], 0.f);
            }
        }
    }
    __syncthreads();

    // ---------- fc2: 50->10 ---------------------------------------------------
    if (tid < IPB * 10) {
        const int im = tid / 10, o = tid % 10;
        const int imgo = min(blockIdx.x * IPB + im, batch - 1);
        float a = bl2[o];
        #pragma unroll
        for (int h = 0; h < 50; ++h)
            a += h1[im * 52 + h] * wl2[o * 50 + h];
        out[(size_t)imgo * 10 + o] = a;          // coalesced
    }
}

extern "C" void kernel_launch(void* const* d_in, const int* in_sizes, int n_in,
                              void* d_out, int out_size, void* d_ws, size_t ws_size,
                              hipStream_t stream) {
    const float* x   = (const float*)d_in[0];
    const float* w1  = (const float*)d_in[1];
    const float* b1  = (const float*)d_in[2];
    const float* w2  = (const float*)d_in[3];
    const float* b2  = (const float*)d_in[4];
    const float* wl1 = (const float*)d_in[5];
    const float* bl1 = (const float*)d_in[6];
    const float* wl2 = (const float*)d_in[7];
    const float* bl2 = (const float*)d_in[8];
    float* out = (float*)d_out;
    unsigned char* ws = (unsigned char*)d_ws;   // 58 KB of packed weights

    const int batch = in_sizes[0] / 784;  // 8192
    pack_weights<<<16, 256, 0, stream>>>(w1, w2, wl1, ws);
    const int grid = (batch + IPB - 1) / IPB;
    lenet_one<<<grid, THREADS, 0, stream>>>(x, ws, b1, b2, bl1, wl2, bl2,
                                            out, batch);
}